// Round 1
// baseline (420.217 us; speedup 1.0000x reference)
//
#include <hip/hip_runtime.h>
#include <hip/hip_bf16.h>
#include <hip/hip_cooperative_groups.h>

namespace cg = cooperative_groups;

#define N_NODES 100000
#define N_EDGES 600000
#define HID 128
#define SCAN_NB 391          // ceil(N_NODES/256)
#define GEMM_BLOCKS 1563     // ceil(N_NODES/64)
#define FILL_BLOCKS 586

// zbuf[n] = 256 bf16: [0:128) y1 = x@W1[0:128] (gathered, src role), [128:256) xbf = bf16(x[n])
// y2buf[n] = 128 bf16: x@W1[128:256] (sequential, tgt role)
// eprs[pos] = (uint src, float-bits w) in CSR-by-target order

typedef short bf16x8 __attribute__((ext_vector_type(8)));
typedef float f32x4  __attribute__((ext_vector_type(4)));

// ---------------- helpers ----------------
__device__ inline unsigned short f2bf(float v) {
    __hip_bfloat16 h = __float2bfloat16(v);
    return *(unsigned short*)&h;
}
__device__ inline float2 bfpair(unsigned int u) {
    float lo = __uint_as_float(u << 16);
    float hi = __uint_as_float(u & 0xffff0000u);
    return make_float2(lo, hi);
}

// ---------------- cooperative CSR: zero+prep | count | scan | rowptr ----------------
__global__ __launch_bounds__(256) void k_csr(const float* __restrict__ W1,
                                             const int* __restrict__ ei,
                                             unsigned short* __restrict__ Bh,
                                             int* __restrict__ deg,
                                             int* __restrict__ partial,
                                             int* __restrict__ rowptr,
                                             int* __restrict__ cursor)
{
    cg::grid_group grid = cg::this_grid();
    const int tid  = threadIdx.x;
    const int b    = blockIdx.x;
    const int gtid = b * 256 + tid;

    // phase 0: zero deg, prep W1[0:256] -> blocked bf16 [ks][n][kl]
    if (gtid < N_NODES) deg[gtid] = 0;
    if (gtid == 0) rowptr[N_NODES] = N_EDGES;
    if (gtid < 32768) {
        int n = gtid & 255;
        int k = gtid >> 8;                           // 0 .. 127
        float v = (n < HID) ? W1[k * HID + n] : W1[(HID + k) * HID + (n - HID)];
        Bh[(k >> 5) * 8192 + n * 32 + (k & 31)] = f2bf(v);
    }
    grid.sync();

    // phase 1: degree count
    for (int e = gtid; e < N_EDGES; e += SCAN_NB * 256)
        atomicAdd(&deg[ei[N_EDGES + e]], 1);
    grid.sync();

    // phase 2: block-local inclusive scan of 256 degrees
    __shared__ int s[256];
    int v = (gtid < N_NODES) ? deg[gtid] : 0;
    s[tid] = v;
    __syncthreads();
    #pragma unroll
    for (int off = 1; off < 256; off <<= 1) {
        int u = (tid >= off) ? s[tid - off] : 0;
        __syncthreads();
        s[tid] += u;
        __syncthreads();
    }
    int incl = s[tid];
    if (tid == 255) partial[b] = incl;
    grid.sync();

    // phase 3: each block sums partial[0..b-1] itself (parallel, no extra sync)
    int acc = 0;
    for (int i = tid; i < b; i += 256) acc += partial[i];
    s[tid] = acc;
    __syncthreads();
    #pragma unroll
    for (int off = 128; off > 0; off >>= 1) {
        if (tid < off) s[tid] += s[tid + off];
        __syncthreads();
    }
    int pb = s[0];
    if (gtid < N_NODES) {
        int r = pb + incl - v;       // exclusive prefix
        rowptr[gtid] = r;
        cursor[gtid] = r;
    }
}

// ---------------- hybrid: K-gemm (MFMA, swapped operands) + CSR fill ----------------
__global__ __launch_bounds__(256) void k_gemm_fill(const float* __restrict__ x,
                                                   const unsigned short* __restrict__ BhG,
                                                   unsigned short* __restrict__ zbuf,
                                                   unsigned short* __restrict__ y2buf,
                                                   const int* __restrict__ ei,
                                                   const float* __restrict__ ew,
                                                   int* __restrict__ cursor,
                                                   uint2* __restrict__ eprs)
{
    __shared__ unsigned short Ah[64 * 32];   // [m][k] 4 KB

    if (blockIdx.x >= GEMM_BLOCKS) {
        // ---- fill role: scatter edges into CSR order ----
        int fb = blockIdx.x - GEMM_BLOCKS;
        for (int e = fb * 256 + threadIdx.x; e < N_EDGES; e += FILL_BLOCKS * 256) {
            int tgt = ei[N_EDGES + e];
            int pos = atomicAdd(&cursor[tgt], 1);
            eprs[pos] = make_uint2((unsigned int)ei[e], __float_as_uint(ew[e]));
        }
        return;
    }

    const int tid  = threadIdx.x;
    const int bm   = blockIdx.x * 64;
    const int wave = tid >> 6;
    const int lane = tid & 63;
    const int q    = lane >> 4;      // 0..3
    const int ln   = lane & 15;      // 0..15

    // stage-A decode: this thread handles (rowA,f4) and (rowB,f4)
    const int rowA = tid >> 3;              // 0..31
    const int rowB = rowA + 32;             // 32..63
    const int f4   = tid & 7;               // 0..7
    const int gmA  = bm + rowA;
    const int gmB  = bm + rowB;
    const bool okA = gmA < N_NODES;
    const bool okB = gmB < N_NODES;
    const float* pxA = &x[(size_t)gmA * HID + f4 * 4];
    const float* pxB = &x[(size_t)gmB * HID + f4 * 4];

    f32x4 acc[4][4] = {};            // [node-tile][out-tile]

    float4 vA = make_float4(0.f,0.f,0.f,0.f), vB = vA;
    float4 vAn = vA, vBn = vA;
    if (okA) vA = *(const float4*)pxA;
    if (okB) vB = *(const float4*)pxB;

    for (int ks = 0; ks < 4; ++ks) {
        const int k0 = ks * 32;
        // ---- stage A: convert current chunk, store LDS + xbf half of zbuf ----
        {
            float4 v = vA;
            unsigned int ph0 = (unsigned int)f2bf(v.x) | ((unsigned int)f2bf(v.y) << 16);
            unsigned int ph1 = (unsigned int)f2bf(v.z) | ((unsigned int)f2bf(v.w) << 16);
            *(uint2*)&Ah[rowA * 32 + f4 * 4] = make_uint2(ph0, ph1);
            if (okA) *(uint2*)&zbuf[(size_t)gmA * 256 + 128 + k0 + f4 * 4] = make_uint2(ph0, ph1);
        }
        {
            float4 v = vB;
            unsigned int ph0 = (unsigned int)f2bf(v.x) | ((unsigned int)f2bf(v.y) << 16);
            unsigned int ph1 = (unsigned int)f2bf(v.z) | ((unsigned int)f2bf(v.w) << 16);
            *(uint2*)&Ah[rowB * 32 + f4 * 4] = make_uint2(ph0, ph1);
            if (okB) *(uint2*)&zbuf[(size_t)gmB * 256 + 128 + k0 + f4 * 4] = make_uint2(ph0, ph1);
        }
        __syncthreads();

        // ---- prefetch next chunk's x (hidden behind ds_read + MFMA) ----
        if (ks < 3) {
            vAn = okA ? *(const float4*)(pxA + (ks + 1) * 32) : make_float4(0.f,0.f,0.f,0.f);
            vBn = okB ? *(const float4*)(pxB + (ks + 1) * 32) : make_float4(0.f,0.f,0.f,0.f);
        }

        // ---- fragments ----
        bf16x8 ah[4], bh[4];
        #pragma unroll
        for (int mt = 0; mt < 4; ++mt) {
            ah[mt] = *(const bf16x8*)&Ah[(mt * 16 + ln) * 32 + q * 8];
        }
        #pragma unroll
        for (int nt = 0; nt < 4; ++nt) {
            bh[nt] = *(const bf16x8*)&BhG[ks * 8192 + (wave * 64 + nt * 16 + ln) * 32 + q * 8];
        }
        // swapped operand order: D = W^T . x^T  -> row = hidden-out, col = node.
        // A/B per-lane fragment layouts are identical (idx=ln, k=q*8+j), so the
        // same staged fragments serve either role; only the epilogue mapping changes.
        #pragma unroll
        for (int mt = 0; mt < 4; ++mt) {
            #pragma unroll
            for (int nt = 0; nt < 4; ++nt) {
                acc[mt][nt] = __builtin_amdgcn_mfma_f32_16x16x32_bf16(bh[nt], ah[mt], acc[mt][nt], 0, 0, 0);
            }
        }
        __syncthreads();
        vA = vAn; vB = vBn;
    }

    // ---- epilogue: D col=ln -> node, row=q*4+r -> hidden-out.
    // Each lane holds 4 consecutive out-cols of one node -> one uint2 (4 bf16) store.
    // 16 x 8B stores/thread vs 64 x 2B before (4x fewer VMEM instructions).
    #pragma unroll
    for (int mt = 0; mt < 4; ++mt) {
        int node = bm + mt * 16 + ln;
        if (node < N_NODES) {
            #pragma unroll
            for (int nt = 0; nt < 4; ++nt) {
                int col0 = wave * 64 + nt * 16 + q * 4;
                unsigned int lo = (unsigned int)f2bf(acc[mt][nt][0]) | ((unsigned int)f2bf(acc[mt][nt][1]) << 16);
                unsigned int hi = (unsigned int)f2bf(acc[mt][nt][2]) | ((unsigned int)f2bf(acc[mt][nt][3]) << 16);
                if (col0 < 128) *(uint2*)&zbuf[(size_t)node * 256 + col0] = make_uint2(lo, hi);
                else            *(uint2*)&y2buf[(size_t)node * 128 + (col0 - 128)] = make_uint2(lo, hi);
            }
        }
    }
}

// ---------------- fused scores + softmax + aggregation (unchanged) ----------------
__global__ __launch_bounds__(256) void k_fused(const unsigned int* __restrict__ zu,
                                               const unsigned int* __restrict__ y2u,
                                               const int* __restrict__ rowptr,
                                               const uint2* __restrict__ eprs,
                                               const float* __restrict__ x,
                                               const float* __restrict__ W1,
                                               const float* __restrict__ b1,
                                               const float* __restrict__ W2,
                                               const float* __restrict__ b2,
                                               float* __restrict__ out)
{
    int n = (blockIdx.x * blockDim.x + threadIdx.x) >> 6;
    int lane = threadIdx.x & 63;
    if (n >= N_NODES) return;
    int ql = lane & 15;      // position within quarter: cols ql*8 .. ql*8+7
    int qi = lane >> 4;      // quarter index 0..3 (edge slot)
    int c0 = ql * 8;

    // per-lane constants for 8 cols
    uint4 uy2 = *(const uint4*)&y2u[(size_t)n * 64 + ql * 4];
    float2 y2a = bfpair(uy2.x), y2b = bfpair(uy2.y), y2c = bfpair(uy2.z), y2d = bfpair(uy2.w);
    float4 bv0 = *(const float4*)&b1[c0];
    float4 bv1 = *(const float4*)&b1[c0 + 4];
    float4 wr0 = *(const float4*)&W1[256 * HID + c0];
    float4 wr1 = *(const float4*)&W1[256 * HID + c0 + 4];
    float4 w20 = *(const float4*)&W2[c0];
    float4 w21 = *(const float4*)&W2[c0 + 4];
    float p0 = y2a.x + bv0.x, p1 = y2a.y + bv0.y, p2 = y2b.x + bv0.z, p3 = y2b.y + bv0.w;
    float p4 = y2c.x + bv1.x, p5 = y2c.y + bv1.y, p6 = y2d.x + bv1.z, p7 = y2d.y + bv1.w;
    float b2v = b2[0];

    int beg = rowptr[n], end = rowptr[n + 1];
    float a0 = 0.f, a1 = 0.f, a2 = 0.f, a3 = 0.f;
    float a4 = 0.f, a5 = 0.f, a6 = 0.f, a7 = 0.f;
    float denom = 0.f;

    for (int i = beg; i < end; i += 4) {
        int idx = i + qi;
        bool valid = idx < end;
        int ie = valid ? idx : (end - 1);
        uint2 ep = eprs[ie];
        size_t base = (size_t)ep.x * 128;
        float w = __uint_as_float(ep.y);
        uint4 uy = *(const uint4*)&zu[base + ql * 4];
        uint4 ux = *(const uint4*)&zu[base + 64 + ql * 4];

        float2 ya = bfpair(uy.x), yb = bfpair(uy.y), yc = bfpair(uy.z), yd = bfpair(uy.w);
        float h0 = fmaxf(fmaf(w, wr0.x, ya.x + p0), 0.f);
        float h1 = fmaxf(fmaf(w, wr0.y, ya.y + p1), 0.f);
        float h2 = fmaxf(fmaf(w, wr0.z, yb.x + p2), 0.f);
        float h3 = fmaxf(fmaf(w, wr0.w, yb.y + p3), 0.f);
        float h4 = fmaxf(fmaf(w, wr1.x, yc.x + p4), 0.f);
        float h5 = fmaxf(fmaf(w, wr1.y, yc.y + p5), 0.f);
        float h6 = fmaxf(fmaf(w, wr1.z, yd.x + p6), 0.f);
        float h7 = fmaxf(fmaf(w, wr1.w, yd.y + p7), 0.f);
        float s = ((h0 * w20.x + h1 * w20.y) + (h2 * w20.z + h3 * w20.w))
                + ((h4 * w21.x + h5 * w21.y) + (h6 * w21.z + h7 * w21.w));
        // reduce within quarter (xor masks 1,2,4,8 stay in the 16-lane group)
        #pragma unroll
        for (int m = 1; m <= 8; m <<= 1) s += __shfl_xor(s, m, 64);
        float es = valid ? __expf(s + b2v) : 0.f;

        float2 xa = bfpair(ux.x), xb = bfpair(ux.y), xc = bfpair(ux.z), xd = bfpair(ux.w);
        a0 = fmaf(es, xa.x, a0); a1 = fmaf(es, xa.y, a1);
        a2 = fmaf(es, xb.x, a2); a3 = fmaf(es, xb.y, a3);
        a4 = fmaf(es, xc.x, a4); a5 = fmaf(es, xc.y, a5);
        a6 = fmaf(es, xd.x, a6); a7 = fmaf(es, xd.y, a7);
        denom += es;
    }

    // merge quarters (each quarter's lane ql covers the same 8 cols)
    #pragma unroll
    for (int m = 16; m <= 32; m <<= 1) {
        a0 += __shfl_xor(a0, m, 64); a1 += __shfl_xor(a1, m, 64);
        a2 += __shfl_xor(a2, m, 64); a3 += __shfl_xor(a3, m, 64);
        a4 += __shfl_xor(a4, m, 64); a5 += __shfl_xor(a5, m, 64);
        a6 += __shfl_xor(a6, m, 64); a7 += __shfl_xor(a7, m, 64);
        denom += __shfl_xor(denom, m, 64);
    }

    if (qi == 0) {
        float4 xt0 = *(const float4*)&x[(size_t)n * HID + c0];
        float4 xt1 = *(const float4*)&x[(size_t)n * HID + c0 + 4];
        float inv = 1.0f / fmaxf(denom, 1e-12f);
        float4 o0, o1;
        o0.x = xt0.x + a0 * inv; o0.y = xt0.y + a1 * inv;
        o0.z = xt0.z + a2 * inv; o0.w = xt0.w + a3 * inv;
        o1.x = xt1.x + a4 * inv; o1.y = xt1.y + a5 * inv;
        o1.z = xt1.z + a6 * inv; o1.w = xt1.w + a7 * inv;
        *(float4*)&out[(size_t)n * HID + c0]     = o0;
        *(float4*)&out[(size_t)n * HID + c0 + 4] = o1;
    }
}

// ---------------- launch ----------------
extern "C" void kernel_launch(void* const* d_in, const int* in_sizes, int n_in,
                              void* d_out, int out_size, void* d_ws, size_t ws_size,
                              hipStream_t stream) {
    const float* x  = (const float*)d_in[0];
    const int*   ei = (const int*)d_in[1];
    const float* ew = (const float*)d_in[2];
    const float* W1 = (const float*)d_in[3];
    const float* b1 = (const float*)d_in[4];
    const float* W2 = (const float*)d_in[5];
    const float* b2 = (const float*)d_in[6];
    float* out = (float*)d_out;
    char* ws = (char*)d_ws;

    const size_t deg_b    = 400000;
    const size_t rowptr_b = 400016;
    const size_t cursor_b = 400000;
    const size_t eprs_b   = 4800000;     // N_EDGES * 8
    const size_t part_b   = 1568;
    const size_t pb_b     = 1568;        // (unused, kept for layout stability)
    const size_t Bh_b     = 65536;

    char* p = ws;
    int* deg      = (int*)p;             p += deg_b;
    int* rowptr   = (int*)p;             p += rowptr_b;
    int* cursor   = (int*)p;             p += cursor_b;
    uint2* eprs   = (uint2*)p;           p += eprs_b;
    int* partial  = (int*)p;             p += part_b;
    p += pb_b;
    unsigned short* BhG = (unsigned short*)p;  p += Bh_b;
    unsigned short* zbuf  = (unsigned short*)p;  p += (size_t)N_NODES * 256 * 2;  // 51.2 MB
    unsigned short* y2buf = (unsigned short*)p;                                   // 25.6 MB

    const int node_wave_blocks = (N_NODES * 64 + 255) / 256;

    // 1) cooperative CSR: zero+prep / count / scan / rowptr  (3 grid syncs)
    void* csr_args[] = {(void*)&W1, (void*)&ei, (void*)&BhG, (void*)&deg,
                        (void*)&partial, (void*)&rowptr, (void*)&cursor};
    hipLaunchCooperativeKernel(k_csr, dim3(SCAN_NB), dim3(256), csr_args, 0u, stream);

    // 2) hybrid: gemm (blocks 0..1562) + fill (blocks 1563..2148)
    hipLaunchKernelGGL(k_gemm_fill, dim3(GEMM_BLOCKS + FILL_BLOCKS), dim3(256), 0, stream,
                       x, BhG, zbuf, y2buf, ei, ew, cursor, eprs);

    // 3) fused scores + softmax + aggregation
    hipLaunchKernelGGL(k_fused, dim3(node_wave_blocks), dim3(256), 0, stream,
                       (const unsigned int*)zbuf, (const unsigned int*)y2buf,
                       rowptr, eprs, x, W1, b1, W2, b2, out);
}

// Round 3
// 270.022 us; speedup vs baseline: 1.5562x; 1.5562x over previous
//
#include <hip/hip_runtime.h>
#include <hip/hip_bf16.h>

#define N_NODES 100000
#define N_EDGES 600000
#define HID 128
#define SCAN_NB 391          // ceil(N_NODES/256)
#define GEMM_BLOCKS 1563     // ceil(N_NODES/64)
#define FILL_BLOCKS 586

// zbuf[n] = 256 bf16: [0:128) y1 = x@W1[0:128] (gathered, src role), [128:256) xbf = bf16(x[n])
// y2buf[n] = 128 bf16: x@W1[128:256] (sequential, tgt role)
// eprs[pos] = (uint src, float-bits w) in CSR-by-target order

typedef short bf16x8 __attribute__((ext_vector_type(8)));
typedef float f32x4  __attribute__((ext_vector_type(4)));

// ---------------- helpers ----------------
__device__ inline unsigned short f2bf(float v) {
    __hip_bfloat16 h = __float2bfloat16(v);
    return *(unsigned short*)&h;
}
__device__ inline float2 bfpair(unsigned int u) {
    float lo = __uint_as_float(u << 16);
    float hi = __uint_as_float(u & 0xffff0000u);
    return make_float2(lo, hi);
}

// ---------------- prep: zero deg + W1[0:256] -> blocked bf16 [ks][n][kl] ----------------
__global__ __launch_bounds__(256) void k_prep(const float* __restrict__ W1,
                                              unsigned short* __restrict__ Bh,
                                              int* __restrict__ deg)
{
    int idx = blockIdx.x * 256 + threadIdx.x;
    if (idx < N_NODES) deg[idx] = 0;
    if (idx < 32768) {
        int n = idx & 255;
        int k = idx >> 8;                            // 0 .. 127
        float v = (n < HID) ? W1[k * HID + n] : W1[(HID + k) * HID + (n - HID)];
        Bh[(k >> 5) * 8192 + n * 32 + (k & 31)] = f2bf(v);
    }
}

// ---------------- CSR: count ----------------
__global__ __launch_bounds__(256) void k_count(const int* __restrict__ ei,
                                               int* __restrict__ deg)
{
    int e = blockIdx.x * blockDim.x + threadIdx.x;
    if (e < N_EDGES) atomicAdd(&deg[ei[N_EDGES + e]], 1);
}

// ---------------- CSR: per-block degree sums ----------------
__global__ __launch_bounds__(256) void k_partial(const int* __restrict__ deg,
                                                 int* __restrict__ partial)
{
    __shared__ int s[256];
    int t = threadIdx.x;
    int idx = blockIdx.x * 256 + t;
    s[t] = (idx < N_NODES) ? deg[idx] : 0;
    __syncthreads();
    #pragma unroll
    for (int off = 128; off > 0; off >>= 1) {
        if (t < off) s[t] += s[t + off];
        __syncthreads();
    }
    if (t == 0) partial[blockIdx.x] = s[0];
}

// ---------------- CSR: rowptr (folds the partial-scan in per-block) ----------------
__global__ __launch_bounds__(256) void k_rowptr(const int* __restrict__ deg,
                                                const int* __restrict__ partial,
                                                int* __restrict__ rowptr,
                                                int* __restrict__ cursor)
{
    __shared__ int sp[256];
    __shared__ int s[256];
    int t = threadIdx.x;
    int b = blockIdx.x;

    // base = sum of partial[0..b-1], computed per-block (391 ints, ~2 loads/thread)
    int acc = 0;
    for (int i = t; i < b; i += 256) acc += partial[i];
    sp[t] = acc;
    __syncthreads();
    #pragma unroll
    for (int off = 128; off > 0; off >>= 1) {
        if (t < off) sp[t] += sp[t + off];
        __syncthreads();
    }
    int pb = sp[0];

    // block-local inclusive scan of degrees
    int idx = b * 256 + t;
    int v = (idx < N_NODES) ? deg[idx] : 0;
    s[t] = v;
    __syncthreads();
    #pragma unroll
    for (int off = 1; off < 256; off <<= 1) {
        int u = (t >= off) ? s[t - off] : 0;
        __syncthreads();
        s[t] += u;
        __syncthreads();
    }
    if (idx < N_NODES) {
        int r = pb + s[t] - v;       // exclusive prefix
        rowptr[idx] = r;
        cursor[idx] = r;
    }
    if (idx == 0) rowptr[N_NODES] = N_EDGES;
}

// ---------------- hybrid: K-gemm (MFMA, swapped operands) + CSR fill ----------------
__global__ __launch_bounds__(256) void k_gemm_fill(const float* __restrict__ x,
                                                   const unsigned short* __restrict__ BhG,
                                                   unsigned short* __restrict__ zbuf,
                                                   unsigned short* __restrict__ y2buf,
                                                   const int* __restrict__ ei,
                                                   const float* __restrict__ ew,
                                                   int* __restrict__ cursor,
                                                   uint2* __restrict__ eprs)
{
    __shared__ unsigned short Ah[64 * 32];   // [m][k] 4 KB

    if (blockIdx.x >= GEMM_BLOCKS) {
        // ---- fill role: scatter edges into CSR order ----
        int fb = blockIdx.x - GEMM_BLOCKS;
        for (int e = fb * 256 + threadIdx.x; e < N_EDGES; e += FILL_BLOCKS * 256) {
            int tgt = ei[N_EDGES + e];
            int pos = atomicAdd(&cursor[tgt], 1);
            eprs[pos] = make_uint2((unsigned int)ei[e], __float_as_uint(ew[e]));
        }
        return;
    }

    const int tid  = threadIdx.x;
    const int bm   = blockIdx.x * 64;
    const int wave = tid >> 6;
    const int lane = tid & 63;
    const int q    = lane >> 4;      // 0..3
    const int ln   = lane & 15;      // 0..15

    // stage-A decode: this thread handles (rowA,f4) and (rowB,f4)
    const int rowA = tid >> 3;              // 0..31
    const int rowB = rowA + 32;             // 32..63
    const int f4   = tid & 7;               // 0..7
    const int gmA  = bm + rowA;
    const int gmB  = bm + rowB;
    const bool okA = gmA < N_NODES;
    const bool okB = gmB < N_NODES;
    const float* pxA = &x[(size_t)gmA * HID + f4 * 4];
    const float* pxB = &x[(size_t)gmB * HID + f4 * 4];

    f32x4 acc[4][4] = {};            // [node-tile][out-tile]

    float4 vA = make_float4(0.f,0.f,0.f,0.f), vB = vA;
    float4 vAn = vA, vBn = vA;
    if (okA) vA = *(const float4*)pxA;
    if (okB) vB = *(const float4*)pxB;

    for (int ks = 0; ks < 4; ++ks) {
        const int k0 = ks * 32;
        // ---- stage A: convert current chunk, store LDS + xbf half of zbuf ----
        {
            float4 v = vA;
            unsigned int ph0 = (unsigned int)f2bf(v.x) | ((unsigned int)f2bf(v.y) << 16);
            unsigned int ph1 = (unsigned int)f2bf(v.z) | ((unsigned int)f2bf(v.w) << 16);
            *(uint2*)&Ah[rowA * 32 + f4 * 4] = make_uint2(ph0, ph1);
            if (okA) *(uint2*)&zbuf[(size_t)gmA * 256 + 128 + k0 + f4 * 4] = make_uint2(ph0, ph1);
        }
        {
            float4 v = vB;
            unsigned int ph0 = (unsigned int)f2bf(v.x) | ((unsigned int)f2bf(v.y) << 16);
            unsigned int ph1 = (unsigned int)f2bf(v.z) | ((unsigned int)f2bf(v.w) << 16);
            *(uint2*)&Ah[rowB * 32 + f4 * 4] = make_uint2(ph0, ph1);
            if (okB) *(uint2*)&zbuf[(size_t)gmB * 256 + 128 + k0 + f4 * 4] = make_uint2(ph0, ph1);
        }
        __syncthreads();

        // ---- prefetch next chunk's x (hidden behind ds_read + MFMA) ----
        if (ks < 3) {
            vAn = okA ? *(const float4*)(pxA + (ks + 1) * 32) : make_float4(0.f,0.f,0.f,0.f);
            vBn = okB ? *(const float4*)(pxB + (ks + 1) * 32) : make_float4(0.f,0.f,0.f,0.f);
        }

        // ---- fragments ----
        bf16x8 ah[4], bh[4];
        #pragma unroll
        for (int mt = 0; mt < 4; ++mt) {
            ah[mt] = *(const bf16x8*)&Ah[(mt * 16 + ln) * 32 + q * 8];
        }
        #pragma unroll
        for (int nt = 0; nt < 4; ++nt) {
            bh[nt] = *(const bf16x8*)&BhG[ks * 8192 + (wave * 64 + nt * 16 + ln) * 32 + q * 8];
        }
        // swapped operand order: D = W^T . x^T  -> row = hidden-out, col = node.
        // A/B per-lane fragment layouts are identical (idx=ln, k=q*8+j), so the
        // same staged fragments serve either role; only the epilogue mapping changes.
        #pragma unroll
        for (int mt = 0; mt < 4; ++mt) {
            #pragma unroll
            for (int nt = 0; nt < 4; ++nt) {
                acc[mt][nt] = __builtin_amdgcn_mfma_f32_16x16x32_bf16(bh[nt], ah[mt], acc[mt][nt], 0, 0, 0);
            }
        }
        __syncthreads();
        vA = vAn; vB = vBn;
    }

    // ---- epilogue: D col=ln -> node, row=q*4+r -> hidden-out.
    // Each lane holds 4 consecutive out-cols of one node -> one uint2 (4 bf16) store.
    #pragma unroll
    for (int mt = 0; mt < 4; ++mt) {
        int node = bm + mt * 16 + ln;
        if (node < N_NODES) {
            #pragma unroll
            for (int nt = 0; nt < 4; ++nt) {
                int col0 = wave * 64 + nt * 16 + q * 4;
                unsigned int lo = (unsigned int)f2bf(acc[mt][nt][0]) | ((unsigned int)f2bf(acc[mt][nt][1]) << 16);
                unsigned int hi = (unsigned int)f2bf(acc[mt][nt][2]) | ((unsigned int)f2bf(acc[mt][nt][3]) << 16);
                if (col0 < 128) *(uint2*)&zbuf[(size_t)node * 256 + col0] = make_uint2(lo, hi);
                else            *(uint2*)&y2buf[(size_t)node * 128 + (col0 - 128)] = make_uint2(lo, hi);
            }
        }
    }
}

// ---------------- fused scores + softmax + aggregation ----------------
__global__ __launch_bounds__(256) void k_fused(const unsigned int* __restrict__ zu,
                                               const unsigned int* __restrict__ y2u,
                                               const int* __restrict__ rowptr,
                                               const uint2* __restrict__ eprs,
                                               const float* __restrict__ x,
                                               const float* __restrict__ W1,
                                               const float* __restrict__ b1,
                                               const float* __restrict__ W2,
                                               const float* __restrict__ b2,
                                               float* __restrict__ out)
{
    int n = (blockIdx.x * blockDim.x + threadIdx.x) >> 6;
    int lane = threadIdx.x & 63;
    if (n >= N_NODES) return;
    int ql = lane & 15;      // position within quarter: cols ql*8 .. ql*8+7
    int qi = lane >> 4;      // quarter index 0..3 (edge slot)
    int c0 = ql * 8;

    // per-lane constants for 8 cols
    uint4 uy2 = *(const uint4*)&y2u[(size_t)n * 64 + ql * 4];
    float2 y2a = bfpair(uy2.x), y2b = bfpair(uy2.y), y2c = bfpair(uy2.z), y2d = bfpair(uy2.w);
    float4 bv0 = *(const float4*)&b1[c0];
    float4 bv1 = *(const float4*)&b1[c0 + 4];
    float4 wr0 = *(const float4*)&W1[256 * HID + c0];
    float4 wr1 = *(const float4*)&W1[256 * HID + c0 + 4];
    float4 w20 = *(const float4*)&W2[c0];
    float4 w21 = *(const float4*)&W2[c0 + 4];
    float p0 = y2a.x + bv0.x, p1 = y2a.y + bv0.y, p2 = y2b.x + bv0.z, p3 = y2b.y + bv0.w;
    float p4 = y2c.x + bv1.x, p5 = y2c.y + bv1.y, p6 = y2d.x + bv1.z, p7 = y2d.y + bv1.w;
    float b2v = b2[0];

    int beg = rowptr[n], end = rowptr[n + 1];
    float a0 = 0.f, a1 = 0.f, a2 = 0.f, a3 = 0.f;
    float a4 = 0.f, a5 = 0.f, a6 = 0.f, a7 = 0.f;
    float denom = 0.f;

    for (int i = beg; i < end; i += 4) {
        int idx = i + qi;
        bool valid = idx < end;
        int ie = valid ? idx : (end - 1);
        uint2 ep = eprs[ie];
        size_t base = (size_t)ep.x * 128;
        float w = __uint_as_float(ep.y);
        uint4 uy = *(const uint4*)&zu[base + ql * 4];
        uint4 ux = *(const uint4*)&zu[base + 64 + ql * 4];

        float2 ya = bfpair(uy.x), yb = bfpair(uy.y), yc = bfpair(uy.z), yd = bfpair(uy.w);
        float h0 = fmaxf(fmaf(w, wr0.x, ya.x + p0), 0.f);
        float h1 = fmaxf(fmaf(w, wr0.y, ya.y + p1), 0.f);
        float h2 = fmaxf(fmaf(w, wr0.z, yb.x + p2), 0.f);
        float h3 = fmaxf(fmaf(w, wr0.w, yb.y + p3), 0.f);
        float h4 = fmaxf(fmaf(w, wr1.x, yc.x + p4), 0.f);
        float h5 = fmaxf(fmaf(w, wr1.y, yc.y + p5), 0.f);
        float h6 = fmaxf(fmaf(w, wr1.z, yd.x + p6), 0.f);
        float h7 = fmaxf(fmaf(w, wr1.w, yd.y + p7), 0.f);
        float s = ((h0 * w20.x + h1 * w20.y) + (h2 * w20.z + h3 * w20.w))
                + ((h4 * w21.x + h5 * w21.y) + (h6 * w21.z + h7 * w21.w));
        // reduce within quarter (xor masks 1,2,4,8 stay in the 16-lane group)
        #pragma unroll
        for (int m = 1; m <= 8; m <<= 1) s += __shfl_xor(s, m, 64);
        float es = valid ? __expf(s + b2v) : 0.f;

        float2 xa = bfpair(ux.x), xb = bfpair(ux.y), xc = bfpair(ux.z), xd = bfpair(ux.w);
        a0 = fmaf(es, xa.x, a0); a1 = fmaf(es, xa.y, a1);
        a2 = fmaf(es, xb.x, a2); a3 = fmaf(es, xb.y, a3);
        a4 = fmaf(es, xc.x, a4); a5 = fmaf(es, xc.y, a5);
        a6 = fmaf(es, xd.x, a6); a7 = fmaf(es, xd.y, a7);
        denom += es;
    }

    // merge quarters (each quarter's lane ql covers the same 8 cols)
    #pragma unroll
    for (int m = 16; m <= 32; m <<= 1) {
        a0 += __shfl_xor(a0, m, 64); a1 += __shfl_xor(a1, m, 64);
        a2 += __shfl_xor(a2, m, 64); a3 += __shfl_xor(a3, m, 64);
        a4 += __shfl_xor(a4, m, 64); a5 += __shfl_xor(a5, m, 64);
        a6 += __shfl_xor(a6, m, 64); a7 += __shfl_xor(a7, m, 64);
        denom += __shfl_xor(denom, m, 64);
    }

    if (qi == 0) {
        float4 xt0 = *(const float4*)&x[(size_t)n * HID + c0];
        float4 xt1 = *(const float4*)&x[(size_t)n * HID + c0 + 4];
        float inv = 1.0f / fmaxf(denom, 1e-12f);
        float4 o0, o1;
        o0.x = xt0.x + a0 * inv; o0.y = xt0.y + a1 * inv;
        o0.z = xt0.z + a2 * inv; o0.w = xt0.w + a3 * inv;
        o1.x = xt1.x + a4 * inv; o1.y = xt1.y + a5 * inv;
        o1.z = xt1.z + a6 * inv; o1.w = xt1.w + a7 * inv;
        *(float4*)&out[(size_t)n * HID + c0]     = o0;
        *(float4*)&out[(size_t)n * HID + c0 + 4] = o1;
    }
}

// ---------------- launch ----------------
extern "C" void kernel_launch(void* const* d_in, const int* in_sizes, int n_in,
                              void* d_out, int out_size, void* d_ws, size_t ws_size,
                              hipStream_t stream) {
    const float* x  = (const float*)d_in[0];
    const int*   ei = (const int*)d_in[1];
    const float* ew = (const float*)d_in[2];
    const float* W1 = (const float*)d_in[3];
    const float* b1 = (const float*)d_in[4];
    const float* W2 = (const float*)d_in[5];
    const float* b2 = (const float*)d_in[6];
    float* out = (float*)d_out;
    char* ws = (char*)d_ws;

    const size_t deg_b    = 400000;
    const size_t rowptr_b = 400016;
    const size_t cursor_b = 400000;
    const size_t eprs_b   = 4800000;     // N_EDGES * 8
    const size_t part_b   = 1568;
    const size_t pb_b     = 1568;        // (unused, kept for layout stability)
    const size_t Bh_b     = 65536;

    char* p = ws;
    int* deg      = (int*)p;             p += deg_b;
    int* rowptr   = (int*)p;             p += rowptr_b;
    int* cursor   = (int*)p;             p += cursor_b;
    uint2* eprs   = (uint2*)p;           p += eprs_b;
    int* partial  = (int*)p;             p += part_b;
    p += pb_b;
    unsigned short* BhG = (unsigned short*)p;  p += Bh_b;
    unsigned short* zbuf  = (unsigned short*)p;  p += (size_t)N_NODES * 256 * 2;  // 51.2 MB
    unsigned short* y2buf = (unsigned short*)p;                                   // 25.6 MB

    const int edge_blocks = (N_EDGES + 255) / 256;
    const int node_wave_blocks = (N_NODES * 64 + 255) / 256;

    hipLaunchKernelGGL(k_prep,   dim3(SCAN_NB), dim3(256), 0, stream, W1, BhG, deg);
    hipLaunchKernelGGL(k_count,  dim3(edge_blocks), dim3(256), 0, stream, ei, deg);
    hipLaunchKernelGGL(k_partial,dim3(SCAN_NB), dim3(256), 0, stream, deg, partial);
    hipLaunchKernelGGL(k_rowptr, dim3(SCAN_NB), dim3(256), 0, stream, deg, partial, rowptr, cursor);
    hipLaunchKernelGGL(k_gemm_fill, dim3(GEMM_BLOCKS + FILL_BLOCKS), dim3(256), 0, stream,
                       x, BhG, zbuf, y2buf, ei, ew, cursor, eprs);
    hipLaunchKernelGGL(k_fused, dim3(node_wave_blocks), dim3(256), 0, stream,
                       (const unsigned int*)zbuf, (const unsigned int*)y2buf,
                       rowptr, eprs, x, W1, b1, W2, b2, out);
}